// Round 1
// baseline (346.731 us; speedup 1.0000x reference)
//
#include <hip/hip_runtime.h>

#define EPS 1e-7f

// ---------------------------------------------------------------------------
// Kernel 1: histogram of destination nodes
// ---------------------------------------------------------------------------
__global__ void hist_kernel(const int* __restrict__ dst, int E,
                            int* __restrict__ count) {
    int e = blockIdx.x * blockDim.x + threadIdx.x;
    if (e < E) atomicAdd(&count[dst[e]], 1);
}

// ---------------------------------------------------------------------------
// Kernel 2: exclusive prefix sum over counts -> offsets[N+1], cursor[N]
// single block, 1024 threads
// ---------------------------------------------------------------------------
__global__ void scan_kernel(const int* __restrict__ count, int N,
                            int* __restrict__ offsets,
                            int* __restrict__ cursor) {
    __shared__ int partial[1024];
    int tid = threadIdx.x;
    int chunk = (N + 1023) >> 10;
    int begin = tid * chunk;
    int end   = begin + chunk;
    if (begin > N) begin = N;
    if (end > N) end = N;

    int sum = 0;
    for (int i = begin; i < end; ++i) sum += count[i];
    partial[tid] = sum;
    __syncthreads();

    // Hillis-Steele inclusive scan over 1024 partials
    for (int off = 1; off < 1024; off <<= 1) {
        int v = (tid >= off) ? partial[tid - off] : 0;
        __syncthreads();
        partial[tid] += v;
        __syncthreads();
    }

    int run = (tid > 0) ? partial[tid - 1] : 0;  // exclusive base for my chunk
    for (int i = begin; i < end; ++i) {
        offsets[i] = run;
        cursor[i]  = run;
        run += count[i];
    }
    if (tid == 0) offsets[N] = partial[1023];
}

// ---------------------------------------------------------------------------
// Kernel 3: bucket src indices by dst (counting-sort scatter)
// ---------------------------------------------------------------------------
__global__ void scatter_kernel(const int* __restrict__ dst,
                               const int* __restrict__ src, int E,
                               int* __restrict__ cursor,
                               int* __restrict__ sorted_src) {
    int e = blockIdx.x * blockDim.x + threadIdx.x;
    if (e < E) {
        int pos = atomicAdd(&cursor[dst[e]], 1);
        sorted_src[pos] = src[e];
    }
}

// ---------------------------------------------------------------------------
// Kernel 4: per-node fused softmax-aggregate + linear
// one wave64 per node; lane = channel. 4 waves (nodes) per block.
//
// Softmax trick: segment-max subtraction cancels in s2/s1 ratio, and
// msg = relu(x)+eps <= ~6 so exp(beta*msg) cannot overflow. One pass.
// ---------------------------------------------------------------------------
__launch_bounds__(256)
__global__ void node_kernel(const float* __restrict__ x,
                            const int* __restrict__ offsets,
                            const int* __restrict__ sorted_src,
                            const float* __restrict__ W,
                            const float* __restrict__ b,
                            const float* __restrict__ beta,
                            float* __restrict__ out, int N) {
    // W stored transposed with stride 65: Wt[c*65 + j] = W[j*64 + c]
    // stride-65 => bank (c+j)%32 on both write and read: 2-way aliasing (free)
    __shared__ float WtS[64 * 65];
    __shared__ float aggS[256];
    __shared__ float bS[64];

    int tid = threadIdx.x;
    for (int idx = tid; idx < 64 * 64; idx += 256) {
        int j = idx >> 6, c = idx & 63;
        WtS[c * 65 + j] = W[idx];
    }
    if (tid < 64) bS[tid] = b[tid];
    __syncthreads();

    const float bt = beta[0];
    const int wave = tid >> 6;
    const int lane = tid & 63;
    const int node = blockIdx.x * 4 + wave;

    float agg = 0.f;
    if (node < N) {
        int start = offsets[node];
        int end   = offsets[node + 1];
        float s1 = 0.f, s2 = 0.f;
        for (int base = start; base < end; base += 64) {
            int cnt = end - base;
            if (cnt > 64) cnt = 64;
            // cooperative load of up to 64 src indices, broadcast via shfl
            int si = (lane < cnt) ? sorted_src[base + lane] : 0;
            for (int k = 0; k < cnt; ++k) {
                int s = __shfl(si, k, 64);
                float v  = x[s * 64 + lane];      // coalesced 256B line
                float m  = fmaxf(v, 0.f) + EPS;   // relu + eps
                float ex = __expf(bt * m);
                s1 += ex;
                s2 += m * ex;
            }
        }
        agg = s2 / (s1 + 1e-16f);   // = sum(msg*alpha); empty segment -> 0
    }
    aggS[tid] = agg;
    __syncthreads();

    if (node < N) {
        float acc = bS[lane];
        const float* as = &aggS[wave * 64];
        #pragma unroll 8
        for (int c = 0; c < 64; ++c) {
            acc = fmaf(as[c], WtS[c * 65 + lane], acc);
        }
        out[node * 64 + lane] = acc;
    }
}

// ---------------------------------------------------------------------------
// launch
// ---------------------------------------------------------------------------
extern "C" void kernel_launch(void* const* d_in, const int* in_sizes, int n_in,
                              void* d_out, int out_size, void* d_ws, size_t ws_size,
                              hipStream_t stream) {
    const float* x    = (const float*)d_in[0];
    const int*   ei   = (const int*)d_in[1];    // [2, E]: row0 = dst, row1 = src
    const float* W    = (const float*)d_in[2];
    const float* b    = (const float*)d_in[3];
    const float* beta = (const float*)d_in[4];
    float* out = (float*)d_out;

    const int N = in_sizes[0] / 64;
    const int E = in_sizes[1] / 2;
    const int* dst = ei;
    const int* src = ei + E;

    // workspace layout (ints), 256B-aligned chunks
    char* ws = (char*)d_ws;
    int* offsets    = (int*)ws;                              // N+1
    int* cursor     = (int*)(ws + ((size_t)(N + 1) * 4 + 255) / 256 * 256);
    int* count      = (int*)((char*)cursor + ((size_t)N * 4 + 255) / 256 * 256);
    int* sorted_src = (int*)((char*)count  + ((size_t)N * 4 + 255) / 256 * 256);

    hipMemsetAsync(count, 0, (size_t)N * 4, stream);

    hist_kernel<<<(E + 255) / 256, 256, 0, stream>>>(dst, E, count);
    scan_kernel<<<1, 1024, 0, stream>>>(count, N, offsets, cursor);
    scatter_kernel<<<(E + 255) / 256, 256, 0, stream>>>(dst, src, E, cursor, sorted_src);
    node_kernel<<<(N + 3) / 4, 256, 0, stream>>>(x, offsets, sorted_src, W, b, beta,
                                                 out, N);
}

// Round 2
// 211.609 us; speedup vs baseline: 1.6385x; 1.6385x over previous
//
#include <hip/hip_runtime.h>

#define EPS 1e-7f

// ---------------------------------------------------------------------------
// Kernel 1: histogram of destination nodes
// ---------------------------------------------------------------------------
__global__ void hist_kernel(const int* __restrict__ dst, int E,
                            int* __restrict__ count) {
    int e = blockIdx.x * blockDim.x + threadIdx.x;
    if (e < E) atomicAdd(&count[dst[e]], 1);
}

// ---------------------------------------------------------------------------
// Scan phase A: per-block sums (1024 threads, chunk of 1024 counts)
// ---------------------------------------------------------------------------
__global__ void scan_sum_kernel(const int* __restrict__ count, int N,
                                int* __restrict__ bsum) {
    __shared__ int wsum[16];
    int i = blockIdx.x * 1024 + threadIdx.x;
    int v = (i < N) ? count[i] : 0;
    #pragma unroll
    for (int d = 32; d > 0; d >>= 1) v += __shfl_down(v, d, 64);
    int wid = threadIdx.x >> 6;
    if ((threadIdx.x & 63) == 0) wsum[wid] = v;
    __syncthreads();
    if (threadIdx.x == 0) {
        int s = 0;
        #pragma unroll
        for (int w = 0; w < 16; ++w) s += wsum[w];
        bsum[blockIdx.x] = s;
    }
}

// ---------------------------------------------------------------------------
// Scan phase B: single wave scans nb (<=64) block sums -> exclusive bases
// ---------------------------------------------------------------------------
__global__ void scan_mid_kernel(const int* __restrict__ bsum, int nb, int N,
                                int* __restrict__ bbase,
                                int* __restrict__ offsets) {
    int lane = threadIdx.x;  // 64 threads = 1 wave
    int v = (lane < nb) ? bsum[lane] : 0;
    int incl = v;
    #pragma unroll
    for (int d = 1; d < 64; d <<= 1) {
        int t = __shfl_up(incl, d, 64);
        if (lane >= d) incl += t;
    }
    if (lane < nb) bbase[lane] = incl - v;
    if (lane == 63) offsets[N] = incl;  // total = E
}

// ---------------------------------------------------------------------------
// Scan phase C: per-element exclusive prefix -> offsets[i], cursor[i]
// ---------------------------------------------------------------------------
__global__ void scan_out_kernel(const int* __restrict__ count, int N,
                                const int* __restrict__ bbase,
                                int* __restrict__ offsets,
                                int* __restrict__ cursor) {
    __shared__ int wsum[16];
    __shared__ int wbase[16];
    int i = blockIdx.x * 1024 + threadIdx.x;
    int lane = threadIdx.x & 63, wid = threadIdx.x >> 6;
    int v = (i < N) ? count[i] : 0;
    int incl = v;
    #pragma unroll
    for (int d = 1; d < 64; d <<= 1) {
        int t = __shfl_up(incl, d, 64);
        if (lane >= d) incl += t;
    }
    if (lane == 63) wsum[wid] = incl;
    __syncthreads();
    if (threadIdx.x == 0) {
        int run = 0;
        #pragma unroll
        for (int w = 0; w < 16; ++w) { wbase[w] = run; run += wsum[w]; }
    }
    __syncthreads();
    if (i < N) {
        int excl = incl - v + wbase[wid] + bbase[blockIdx.x];
        offsets[i] = excl;
        cursor[i]  = excl;
    }
}

// ---------------------------------------------------------------------------
// Kernel 3: bucket src indices by dst (counting-sort scatter)
// ---------------------------------------------------------------------------
__global__ void scatter_kernel(const int* __restrict__ dst,
                               const int* __restrict__ src, int E,
                               int* __restrict__ cursor,
                               int* __restrict__ sorted_src) {
    int e = blockIdx.x * blockDim.x + threadIdx.x;
    if (e < E) {
        int pos = atomicAdd(&cursor[dst[e]], 1);
        sorted_src[pos] = src[e];
    }
}

// ---------------------------------------------------------------------------
// Kernel 4: per-node fused softmax-aggregate + linear.
// Grid-stride over nodes: W staged to LDS once per block (2048 blocks,
// not 12500), bias in register. Gather loop unrolled 8-wide with
// independent loads (predicated accumulate, no serial tail) for MLP.
// ---------------------------------------------------------------------------
__launch_bounds__(256)
__global__ void node_kernel(const float* __restrict__ x,
                            const int* __restrict__ offsets,
                            const int* __restrict__ sorted_src,
                            const float* __restrict__ W,
                            const float* __restrict__ b,
                            const float* __restrict__ beta,
                            float* __restrict__ out, int N) {
    // W transposed, stride 65: 2-way bank aliasing on reads = free (m136)
    __shared__ float WtS[64 * 65];
    __shared__ float aggS[256];

    int tid = threadIdx.x;
    for (int idx = tid * 4; idx < 64 * 64; idx += 256 * 4) {
        float4 w4 = *(const float4*)&W[idx];
        int j = idx >> 6, c = idx & 63;
        WtS[(c + 0) * 65 + j] = w4.x;
        WtS[(c + 1) * 65 + j] = w4.y;
        WtS[(c + 2) * 65 + j] = w4.z;
        WtS[(c + 3) * 65 + j] = w4.w;
    }
    __syncthreads();

    const float bt = beta[0];
    const int wave = tid >> 6;
    const int lane = tid & 63;
    const float bias = b[lane];
    const int stride = gridDim.x * 4;
    float* as = &aggS[wave * 64];  // wave-private; no cross-wave sync needed

    for (int node = blockIdx.x * 4 + wave; node < N; node += stride) {
        int start = offsets[node];
        int end   = offsets[node + 1];
        float s1 = 0.f, s2 = 0.f;
        for (int base = start; base < end; base += 64) {
            int cnt = end - base;
            if (cnt > 64) cnt = 64;
            // premultiplied row offset; 0 for inactive lanes (safe address)
            int si = (lane < cnt) ? (sorted_src[base + lane] << 6) : 0;
            for (int k = 0; k < cnt; k += 8) {
                int o[8];
                #pragma unroll
                for (int j = 0; j < 8; ++j) o[j] = __shfl(si, k + j, 64);
                float v[8];
                #pragma unroll
                for (int j = 0; j < 8; ++j) v[j] = x[o[j] + lane];
                #pragma unroll
                for (int j = 0; j < 8; ++j) {
                    float m  = fmaxf(v[j], 0.f) + EPS;
                    float ex = __expf(bt * m);
                    bool ok  = (k + j) < cnt;
                    s1 += ok ? ex : 0.f;
                    s2 += ok ? m * ex : 0.f;
                }
            }
        }
        float agg = s2 / (s1 + 1e-16f);
        as[lane] = agg;  // same-wave DS ops are in-order; lgkmcnt guards RAW
        float acc = bias;
        #pragma unroll
        for (int c = 0; c < 64; c += 4) {
            float4 a4 = *(const float4*)&as[c];  // uniform addr -> b128 broadcast
            acc = fmaf(a4.x, WtS[(c + 0) * 65 + lane], acc);
            acc = fmaf(a4.y, WtS[(c + 1) * 65 + lane], acc);
            acc = fmaf(a4.z, WtS[(c + 2) * 65 + lane], acc);
            acc = fmaf(a4.w, WtS[(c + 3) * 65 + lane], acc);
        }
        out[(size_t)node * 64 + lane] = acc;
    }
}

// ---------------------------------------------------------------------------
// launch
// ---------------------------------------------------------------------------
extern "C" void kernel_launch(void* const* d_in, const int* in_sizes, int n_in,
                              void* d_out, int out_size, void* d_ws, size_t ws_size,
                              hipStream_t stream) {
    const float* x    = (const float*)d_in[0];
    const int*   ei   = (const int*)d_in[1];    // [2, E]: row0 = dst, row1 = src
    const float* W    = (const float*)d_in[2];
    const float* b    = (const float*)d_in[3];
    const float* beta = (const float*)d_in[4];
    float* out = (float*)d_out;

    const int N = in_sizes[0] / 64;
    const int E = in_sizes[1] / 2;
    const int* dst = ei;
    const int* src = ei + E;

    // workspace layout (ints), 256B-aligned chunks
    char* ws = (char*)d_ws;
    auto align = [](size_t v) { return (v + 255) / 256 * 256; };
    int* offsets    = (int*)ws;                                         // N+1
    int* cursor     = (int*)(ws + align((size_t)(N + 1) * 4));          // N
    int* count      = (int*)((char*)cursor + align((size_t)N * 4));     // N
    int* bsum       = (int*)((char*)count + align((size_t)N * 4));      // 64
    int* bbase      = bsum + 64;                                        // 64
    int* sorted_src = (int*)((char*)bsum + 256 + 256);                  // E

    const int nb = (N + 1023) / 1024;  // 49 for N=50000 (must be <= 64)

    hipMemsetAsync(count, 0, (size_t)N * 4, stream);
    hist_kernel<<<(E + 255) / 256, 256, 0, stream>>>(dst, E, count);
    scan_sum_kernel<<<nb, 1024, 0, stream>>>(count, N, bsum);
    scan_mid_kernel<<<1, 64, 0, stream>>>(bsum, nb, N, bbase, offsets);
    scan_out_kernel<<<nb, 1024, 0, stream>>>(count, N, bbase, offsets, cursor);
    scatter_kernel<<<(E + 255) / 256, 256, 0, stream>>>(dst, src, E, cursor, sorted_src);

    int node_blocks = (N + 3) / 4;
    if (node_blocks > 2048) node_blocks = 2048;  // 8 blocks/CU (LDS-limited)
    node_kernel<<<node_blocks, 256, 0, stream>>>(x, offsets, sorted_src, W, b, beta,
                                                 out, N);
}

// Round 3
// 155.151 us; speedup vs baseline: 2.2348x; 1.3639x over previous
//
#include <hip/hip_runtime.h>

#define EPS 1e-7f

__device__ __forceinline__ unsigned bf16_rne(float f) {
    unsigned u = __float_as_uint(f);
    return (u + 0x7fffu + ((u >> 16) & 1u)) >> 16;
}

// ---------------------------------------------------------------------------
// Phase 1a: coarse histogram, bucket = dst>>8 (256 nodes/bucket), LDS-agg.
// ---------------------------------------------------------------------------
__global__ void coarse_hist_kernel(const int* __restrict__ dst, int E,
                                   int* __restrict__ ccount) {
    __shared__ int lc[256];
    int tid = threadIdx.x;
    lc[tid] = 0;
    __syncthreads();
    int e0 = blockIdx.x * 2048;
    #pragma unroll
    for (int i = 0; i < 8; ++i) {
        int e = e0 + i * 256 + tid;
        if (e < E) atomicAdd(&lc[dst[e] >> 8], 1);
    }
    __syncthreads();
    int c = lc[tid];
    if (c) atomicAdd(&ccount[tid], c);
}

// ---------------------------------------------------------------------------
// Phase 1b: scan 196 bucket counts (single block). cbase = pristine bases,
// ccur = running cursors for bin_kernel. Also offsets[N] = E.
// ---------------------------------------------------------------------------
__global__ void cscan_kernel(const int* __restrict__ ccount, int NB, int N,
                             int* __restrict__ cbase, int* __restrict__ ccur,
                             int* __restrict__ offsets) {
    __shared__ int wsum[4];
    int tid = threadIdx.x;
    int lane = tid & 63, wid = tid >> 6;
    int v = (tid < NB) ? ccount[tid] : 0;
    int incl = v;
    #pragma unroll
    for (int d = 1; d < 64; d <<= 1) {
        int t = __shfl_up(incl, d, 64);
        if (lane >= d) incl += t;
    }
    if (lane == 63) wsum[wid] = incl;
    __syncthreads();
    int base = 0;
    for (int w = 0; w < wid; ++w) base += wsum[w];
    int excl = base + incl - v;
    if (tid <= NB) cbase[tid] = excl;
    if (tid < NB) ccur[tid] = excl;
    if (tid == NB) offsets[N] = excl;
}

// ---------------------------------------------------------------------------
// Phase 1c: bin edges into coarse buckets. Packed entry: (dst&255)<<16 | src
// (valid: N < 65536). Same-bucket edges from one block land in consecutive
// global slots -> ~full-line writes (kills the 16x write amplification).
// ---------------------------------------------------------------------------
__global__ void bin_kernel(const int* __restrict__ dst,
                           const int* __restrict__ src, int E,
                           int* __restrict__ ccur,
                           unsigned* __restrict__ packed) {
    __shared__ int lc[256];
    __shared__ int lbase[256];
    int tid = threadIdx.x;
    lc[tid] = 0;
    __syncthreads();
    int e0 = blockIdx.x * 2048;
    int bb[8], rr[8];
    #pragma unroll
    for (int i = 0; i < 8; ++i) {
        int e = e0 + i * 256 + tid;
        bb[i] = 0; rr[i] = 0;
        if (e < E) { bb[i] = dst[e] >> 8; rr[i] = atomicAdd(&lc[bb[i]], 1); }
    }
    __syncthreads();
    int c = lc[tid];
    if (c) lbase[tid] = atomicAdd(&ccur[tid], c);
    __syncthreads();
    #pragma unroll
    for (int i = 0; i < 8; ++i) {
        int e = e0 + i * 256 + tid;
        if (e < E)
            packed[lbase[bb[i]] + rr[i]] =
                ((unsigned)(dst[e] & 255) << 16) | (unsigned)src[e];
    }
}

// ---------------------------------------------------------------------------
// Phase 2: one block per bucket. In-LDS hist of dst-low-byte -> in-LDS scan
// -> per-node CSR offsets (coalesced write) + in-LDS-cursor fine scatter into
// the bucket's contiguous ~16KB output window. Replaces global hist + 3-phase
// scan + global-cursor scatter.
// ---------------------------------------------------------------------------
__global__ void fine_kernel(const unsigned* __restrict__ packed,
                            const int* __restrict__ cbase,
                            int* __restrict__ offsets,
                            int* __restrict__ sorted_src, int N) {
    __shared__ int lc[256];
    __shared__ int lcur[256];
    __shared__ int wsum[4];
    int tid = threadIdx.x, b = blockIdx.x;
    int rs = cbase[b], re = cbase[b + 1];
    lc[tid] = 0;
    __syncthreads();
    for (int i = rs + tid; i < re; i += 256)
        atomicAdd(&lc[packed[i] >> 16], 1);
    __syncthreads();
    // 256-wide exclusive scan of lc
    int lane = tid & 63, wid = tid >> 6;
    int v = lc[tid];
    int incl = v;
    #pragma unroll
    for (int d = 1; d < 64; d <<= 1) {
        int t = __shfl_up(incl, d, 64);
        if (lane >= d) incl += t;
    }
    if (lane == 63) wsum[wid] = incl;
    __syncthreads();
    int base = 0;
    for (int w = 0; w < wid; ++w) base += wsum[w];
    int excl = base + incl - v;
    lcur[tid] = excl;
    int node = b * 256 + tid;
    if (node < N) offsets[node] = rs + excl;
    __syncthreads();
    for (int i = rs + tid; i < re; i += 256) {
        unsigned u = packed[i];
        int pos = atomicAdd(&lcur[u >> 16], 1);
        sorted_src[rs + pos] = (int)(u & 0xffffu);
    }
}

// ---------------------------------------------------------------------------
// Precompute t[n][c] = pack_bf16( exp(beta*m), m*exp(beta*m) ), m=relu(x)+eps.
// Row N is all-zero: padding lanes in node_kernel gather exact 0.
// ---------------------------------------------------------------------------
__global__ void prep_kernel(const float* __restrict__ x,
                            const float* __restrict__ beta,
                            unsigned* __restrict__ t, int M) {
    int i = blockIdx.x * 256 + threadIdx.x;
    if (i < M) {
        float m  = fmaxf(x[i], 0.f) + EPS;
        float ex = __expf(beta[0] * m);
        t[i] = bf16_rne(ex) | (bf16_rne(m * ex) << 16);
    } else if (i < M + 64) {
        t[i] = 0u;
    }
}

// ---------------------------------------------------------------------------
// Per-node fused softmax-aggregate + linear. USE_T: gather precomputed
// bf16x2 table (no exp/relu in the 51M-scale loop); padding lanes point at
// the zero row (no predication). Epilogue: agg @ W^T from LDS.
// ---------------------------------------------------------------------------
template <bool USE_T>
__launch_bounds__(256)
__global__ void node_kernel(const float* __restrict__ x,
                            const unsigned* __restrict__ t,
                            const int* __restrict__ offsets,
                            const int* __restrict__ sorted_src,
                            const float* __restrict__ W,
                            const float* __restrict__ b,
                            const float* __restrict__ beta,
                            float* __restrict__ out, int N) {
    // W transposed, stride 65: 2-way bank aliasing on reads = free (m136)
    __shared__ float WtS[64 * 65];
    __shared__ float aggS[256];

    int tid = threadIdx.x;
    for (int idx = tid * 4; idx < 64 * 64; idx += 256 * 4) {
        float4 w4 = *(const float4*)&W[idx];
        int j = idx >> 6, c = idx & 63;
        WtS[(c + 0) * 65 + j] = w4.x;
        WtS[(c + 1) * 65 + j] = w4.y;
        WtS[(c + 2) * 65 + j] = w4.z;
        WtS[(c + 3) * 65 + j] = w4.w;
    }
    __syncthreads();

    const float bt = beta[0];
    const int wave = tid >> 6;
    const int lane = tid & 63;
    const float bias = b[lane];
    const int stride = gridDim.x * 4;
    const int zero_off = N << 6;
    float* as = &aggS[wave * 64];  // wave-private; in-order DS pipe

    for (int node = blockIdx.x * 4 + wave; node < N; node += stride) {
        int start = offsets[node];
        int end   = offsets[node + 1];
        float s1 = 0.f, s2 = 0.f;
        for (int base = start; base < end; base += 64) {
            int cnt = end - base;
            if (cnt > 64) cnt = 64;
            if (USE_T) {
                // padding lanes -> zero row: contributes exactly 0, no cndmask
                int si = (lane < cnt) ? (sorted_src[base + lane] << 6) : zero_off;
                for (int k = 0; k < cnt; k += 8) {
                    int o[8];
                    #pragma unroll
                    for (int j = 0; j < 8; ++j) o[j] = __shfl(si, k + j, 64);
                    unsigned u[8];
                    #pragma unroll
                    for (int j = 0; j < 8; ++j) u[j] = t[o[j] + lane];
                    #pragma unroll
                    for (int j = 0; j < 8; ++j) {
                        s1 += __uint_as_float(u[j] << 16);
                        s2 += __uint_as_float(u[j] & 0xffff0000u);
                    }
                }
            } else {
                int si = (lane < cnt) ? (sorted_src[base + lane] << 6) : 0;
                for (int k = 0; k < cnt; k += 8) {
                    int o[8];
                    #pragma unroll
                    for (int j = 0; j < 8; ++j) o[j] = __shfl(si, k + j, 64);
                    float vv[8];
                    #pragma unroll
                    for (int j = 0; j < 8; ++j) vv[j] = x[o[j] + lane];
                    #pragma unroll
                    for (int j = 0; j < 8; ++j) {
                        float m  = fmaxf(vv[j], 0.f) + EPS;
                        float ex = __expf(bt * m);
                        bool ok  = (k + j) < cnt;
                        s1 += ok ? ex : 0.f;
                        s2 += ok ? m * ex : 0.f;
                    }
                }
            }
        }
        float agg = s2 / (s1 + 1e-16f);
        as[lane] = agg;
        float acc = bias;
        #pragma unroll
        for (int c = 0; c < 64; c += 4) {
            float4 a4 = *(const float4*)&as[c];  // uniform addr -> b128 broadcast
            acc = fmaf(a4.x, WtS[(c + 0) * 65 + lane], acc);
            acc = fmaf(a4.y, WtS[(c + 1) * 65 + lane], acc);
            acc = fmaf(a4.z, WtS[(c + 2) * 65 + lane], acc);
            acc = fmaf(a4.w, WtS[(c + 3) * 65 + lane], acc);
        }
        out[(size_t)node * 64 + lane] = acc;
    }
}

// ---------------------------------------------------------------------------
// launch
// ---------------------------------------------------------------------------
extern "C" void kernel_launch(void* const* d_in, const int* in_sizes, int n_in,
                              void* d_out, int out_size, void* d_ws, size_t ws_size,
                              hipStream_t stream) {
    const float* x    = (const float*)d_in[0];
    const int*   ei   = (const int*)d_in[1];    // [2, E]: row0 = dst, row1 = src
    const float* W    = (const float*)d_in[2];
    const float* b    = (const float*)d_in[3];
    const float* beta = (const float*)d_in[4];
    float* out = (float*)d_out;

    const int N = in_sizes[0] / 64;
    const int E = in_sizes[1] / 2;
    const int* dst = ei;
    const int* src = ei + E;
    const int NB = (N + 255) >> 8;              // 196 coarse buckets

    auto align = [](size_t v) { return (v + 255) & ~(size_t)255; };
    size_t off = 0;
    char* ws = (char*)d_ws;
    int* offsets = (int*)(ws + off);      off += align((size_t)(N + 1) * 4);
    int* ccount  = (int*)(ws + off);      off += align(256 * 4);
    int* cbase   = (int*)(ws + off);      off += align(257 * 4);
    int* ccur    = (int*)(ws + off);      off += align(256 * 4);
    unsigned* packed = (unsigned*)(ws + off); off += align((size_t)E * 4);
    int* sorted_src  = (int*)(ws + off);  off += align((size_t)E * 4);
    unsigned* t = (unsigned*)(ws + off);
    size_t need_t = off + align(((size_t)N + 1) * 64 * 4);
    const bool use_t = (ws_size >= need_t);

    const int nchunk = (E + 2047) / 2048;

    hipMemsetAsync(ccount, 0, 256 * 4, stream);
    coarse_hist_kernel<<<nchunk, 256, 0, stream>>>(dst, E, ccount);
    cscan_kernel<<<1, 256, 0, stream>>>(ccount, NB, N, cbase, ccur, offsets);
    bin_kernel<<<nchunk, 256, 0, stream>>>(dst, src, E, ccur, packed);
    fine_kernel<<<NB, 256, 0, stream>>>(packed, cbase, offsets, sorted_src, N);
    if (use_t) {
        prep_kernel<<<((N + 1) * 64 + 255) / 256, 256, 0, stream>>>(x, beta, t, N * 64);
    }

    int node_blocks = (N + 3) / 4;
    if (node_blocks > 2048) node_blocks = 2048;  // 8 blocks/CU (LDS-limited)
    if (use_t) {
        node_kernel<true><<<node_blocks, 256, 0, stream>>>(
            x, t, offsets, sorted_src, W, b, beta, out, N);
    } else {
        node_kernel<false><<<node_blocks, 256, 0, stream>>>(
            x, t, offsets, sorted_src, W, b, beta, out, N);
    }
}

// Round 4
// 143.587 us; speedup vs baseline: 2.4148x; 1.0805x over previous
//
#include <hip/hip_runtime.h>
#include <hip/hip_fp16.h>

#define EPS 1e-7f

// ---------------------------------------------------------------------------
// Phase 1: bin edges into 256-node coarse buckets with FIXED-CAPACITY windows
// (bucket b owns packed[b*cap .. b*cap+cap)). LDS-ranked so each block writes
// ~10-entry contiguous runs per bucket (low write amplification). No global
// histogram / scan needed. Packed entry: (dst&255)<<16 | src  (needs N<65536).
// ---------------------------------------------------------------------------
__global__ void bin_kernel(const int* __restrict__ dst,
                           const int* __restrict__ src, int E, int cap,
                           int* __restrict__ ccur,
                           unsigned* __restrict__ packed) {
    __shared__ int lc[256];
    __shared__ int lbase[256];
    int tid = threadIdx.x;
    lc[tid] = 0;
    __syncthreads();
    int e0 = blockIdx.x * 2048;
    int bb[8], rr[8];
    #pragma unroll
    for (int i = 0; i < 8; ++i) {
        int e = e0 + i * 256 + tid;
        bb[i] = 0; rr[i] = 0;
        if (e < E) { bb[i] = dst[e] >> 8; rr[i] = atomicAdd(&lc[bb[i]], 1); }
    }
    __syncthreads();
    int c = lc[tid];
    if (c) lbase[tid] = tid * cap + atomicAdd(&ccur[tid], c);  // ccur zeroed
    __syncthreads();
    #pragma unroll
    for (int i = 0; i < 8; ++i) {
        int e = e0 + i * 256 + tid;
        if (e < E)
            packed[lbase[bb[i]] + rr[i]] =
                ((unsigned)(dst[e] & 255) << 16) | (unsigned)src[e];
    }
}

// ---------------------------------------------------------------------------
// Phase 2: one block per bucket. In-LDS hist of dst-low-byte -> in-LDS scan
// -> exact per-node [nstart,nend) + fine scatter (u16 src) into the bucket's
// contiguous window. Inter-bucket gaps are fine: node_kernel reads start+end.
// ---------------------------------------------------------------------------
__global__ void fine_kernel(const unsigned* __restrict__ packed,
                            const int* __restrict__ ccur, int cap,
                            int* __restrict__ nstart, int* __restrict__ nend,
                            unsigned short* __restrict__ sorted_src, int N) {
    __shared__ int lc[256];
    __shared__ int lcur[256];
    __shared__ int wsum[4];
    int tid = threadIdx.x, b = blockIdx.x;
    int rs = b * cap;
    int re = rs + ccur[b];
    lc[tid] = 0;
    __syncthreads();
    for (int i = rs + tid; i < re; i += 256)
        atomicAdd(&lc[packed[i] >> 16], 1);
    __syncthreads();
    // 256-wide exclusive scan of lc
    int lane = tid & 63, wid = tid >> 6;
    int v = lc[tid];
    int incl = v;
    #pragma unroll
    for (int d = 1; d < 64; d <<= 1) {
        int t = __shfl_up(incl, d, 64);
        if (lane >= d) incl += t;
    }
    if (lane == 63) wsum[wid] = incl;
    __syncthreads();
    int base = 0;
    for (int w = 0; w < wid; ++w) base += wsum[w];
    int excl = base + incl - v;
    lcur[tid] = excl;
    int node = b * 256 + tid;
    if (node < N) { nstart[node] = rs + excl; nend[node] = rs + excl + v; }
    __syncthreads();
    for (int i = rs + tid; i < re; i += 256) {
        unsigned u = packed[i];
        int pos = atomicAdd(&lcur[u >> 16], 1);
        sorted_src[rs + pos] = (unsigned short)(u & 0xffffu);
    }
}

// ---------------------------------------------------------------------------
// Precompute t[n][c] = pack_fp16( exp(beta*m), m*exp(beta*m) ), m=relu(x)+eps.
// fp16 (not bf16): 4x lower quant error; range <= ~1400 at beta=1, no overflow.
// Row N is all-zero so padding lanes/edges in node_kernel contribute exact 0.
// ---------------------------------------------------------------------------
__global__ void prep_kernel(const float* __restrict__ x,
                            const float* __restrict__ beta,
                            unsigned* __restrict__ t, int M) {
    int i = blockIdx.x * 256 + threadIdx.x;
    if (i < M) {
        float m  = fmaxf(x[i], 0.f) + EPS;
        float ex = __expf(beta[0] * m);
        unsigned a = (unsigned)__half_as_ushort(__float2half_rn(ex));
        unsigned c = (unsigned)__half_as_ushort(__float2half_rn(m * ex));
        t[i] = a | (c << 16);
    } else if (i < M + 64) {
        t[i] = 0u;
    }
}

__device__ __forceinline__ float h_lo(unsigned u) {
    return __half2float(__ushort_as_half((unsigned short)(u & 0xffffu)));
}
__device__ __forceinline__ float h_hi(unsigned u) {
    return __half2float(__ushort_as_half((unsigned short)(u >> 16)));
}

// ---------------------------------------------------------------------------
// Per-node fused softmax-aggregate + linear. Paired-edge gather: lower half-
// wave processes even edges, upper half odd; each lane owns channel pair
// (2*(lane&31), +1) via one dwordx2 -> half the gather/shfl instructions.
// shfl_xor(32) combines halves. Epilogue: agg @ W^T from LDS (stride 65).
// ---------------------------------------------------------------------------
__launch_bounds__(256)
__global__ void node_kernel(const unsigned* __restrict__ t,
                            const int* __restrict__ nstart,
                            const int* __restrict__ nend,
                            const unsigned short* __restrict__ sorted_src,
                            const float* __restrict__ W,
                            const float* __restrict__ b,
                            float* __restrict__ out, int N) {
    __shared__ float WtS[64 * 65];
    __shared__ float aggS[256];

    int tid = threadIdx.x;
    for (int idx = tid * 4; idx < 64 * 64; idx += 256 * 4) {
        float4 w4 = *(const float4*)&W[idx];
        int j = idx >> 6, c = idx & 63;
        WtS[(c + 0) * 65 + j] = w4.x;
        WtS[(c + 1) * 65 + j] = w4.y;
        WtS[(c + 2) * 65 + j] = w4.z;
        WtS[(c + 3) * 65 + j] = w4.w;
    }
    __syncthreads();

    const int wave = tid >> 6;
    const int lane = tid & 63;
    const int half = lane >> 5;          // 0: even edges, 1: odd edges
    const int choff = (lane & 31) << 1;  // channel pair base
    const float bias = b[lane];
    const int stride = gridDim.x * 4;
    const int zero_row = N << 6;
    float* as = &aggS[wave * 64];  // wave-private

    for (int node = blockIdx.x * 4 + wave; node < N; node += stride) {
        int start = nstart[node];
        int end   = nend[node];
        float s1a = 0.f, s2a = 0.f, s1b = 0.f, s2b = 0.f;
        for (int bse = start; bse < end; bse += 64) {
            int cnt = end - bse;
            if (cnt > 64) cnt = 64;
            // padding lanes -> zero row (contributes exact 0, no predication)
            int row = (lane < cnt) ? ((int)sorted_src[bse + lane] << 6)
                                   : zero_row;
            for (int k = 0; k < cnt; k += 8) {
                int r[4];
                #pragma unroll
                for (int j = 0; j < 4; ++j)
                    r[j] = __shfl(row, k + 2 * j + half, 64);  // bpermute
                uint2 u[4];
                #pragma unroll
                for (int j = 0; j < 4; ++j)
                    u[j] = *(const uint2*)&t[r[j] + choff];
                #pragma unroll
                for (int j = 0; j < 4; ++j) {
                    s1a += h_lo(u[j].x); s2a += h_hi(u[j].x);
                    s1b += h_lo(u[j].y); s2b += h_hi(u[j].y);
                }
            }
        }
        s1a += __shfl_xor(s1a, 32, 64); s2a += __shfl_xor(s2a, 32, 64);
        s1b += __shfl_xor(s1b, 32, 64); s2b += __shfl_xor(s2b, 32, 64);
        float g0 = s2a / (s1a + 1e-16f);
        float g1 = s2b / (s1b + 1e-16f);
        if (lane < 32) { as[choff] = g0; as[choff + 1] = g1; }
        float acc = bias;
        #pragma unroll
        for (int c = 0; c < 64; c += 4) {
            float4 a4 = *(const float4*)&as[c];  // uniform addr -> broadcast
            acc = fmaf(a4.x, WtS[(c + 0) * 65 + lane], acc);
            acc = fmaf(a4.y, WtS[(c + 1) * 65 + lane], acc);
            acc = fmaf(a4.z, WtS[(c + 2) * 65 + lane], acc);
            acc = fmaf(a4.w, WtS[(c + 3) * 65 + lane], acc);
        }
        out[(size_t)node * 64 + lane] = acc;
    }
}

// ---------------------------------------------------------------------------
// launch
// ---------------------------------------------------------------------------
extern "C" void kernel_launch(void* const* d_in, const int* in_sizes, int n_in,
                              void* d_out, int out_size, void* d_ws, size_t ws_size,
                              hipStream_t stream) {
    const float* x    = (const float*)d_in[0];
    const int*   ei   = (const int*)d_in[1];    // [2, E]: row0 = dst, row1 = src
    const float* W    = (const float*)d_in[2];
    const float* b    = (const float*)d_in[3];
    const float* beta = (const float*)d_in[4];
    float* out = (float*)d_out;

    const int N = in_sizes[0] / 64;
    const int E = in_sizes[1] / 2;
    const int* dst = ei;
    const int* src = ei + E;
    const int NB = (N + 255) >> 8;              // 196 coarse buckets

    // fixed per-bucket capacity: mean + 50% + 256, rounded up to 256
    int cap = (E + NB - 1) / NB;
    cap = ((cap + cap / 2 + 256) + 255) & ~255;

    auto align = [](size_t v) { return (v + 255) & ~(size_t)255; };
    size_t off = 0;
    char* ws = (char*)d_ws;
    int* nstart = (int*)(ws + off);       off += align((size_t)N * 4);
    int* nend   = (int*)(ws + off);       off += align((size_t)N * 4);
    int* ccur   = (int*)(ws + off);       off += align((size_t)NB * 4);
    unsigned* packed = (unsigned*)(ws + off);
    off += align((size_t)NB * cap * 4);
    unsigned short* sorted_src = (unsigned short*)(ws + off);
    off += align((size_t)NB * cap * 2);
    unsigned* t = (unsigned*)(ws + off);  // (N+1)*64 entries, row N = zeros

    const int nchunk = (E + 2047) / 2048;

    hipMemsetAsync(ccur, 0, (size_t)NB * 4, stream);
    bin_kernel<<<nchunk, 256, 0, stream>>>(dst, src, E, cap, ccur, packed);
    fine_kernel<<<NB, 256, 0, stream>>>(packed, ccur, cap, nstart, nend,
                                        sorted_src, N);
    prep_kernel<<<((N + 1) * 64 + 255) / 256, 256, 0, stream>>>(x, beta, t, N * 64);

    int node_blocks = (N + 3) / 4;
    if (node_blocks > 2048) node_blocks = 2048;  // ~8 blocks/CU (LDS-limited)
    node_kernel<<<node_blocks, 256, 0, stream>>>(t, nstart, nend, sorted_src,
                                                 W, b, out, N);
}

// Round 5
// 136.501 us; speedup vs baseline: 2.5401x; 1.0519x over previous
//
#include <hip/hip_runtime.h>
#include <hip/hip_fp16.h>

#define EPS 1e-7f

// ---------------------------------------------------------------------------
// Fused Phase 1: blocks [0, binBlocks) bin edges into 256-node coarse buckets
// with fixed-capacity windows (LDS-ranked -> contiguous runs, low write amp);
// blocks [binBlocks, ...) build the fp16 message table tm[n][c] = relu(x)+eps,
// with sentinel row N = -32 (exp(beta*-32) ~ 1e-14: padding contributes 0).
// Packed entry: (dst&255)<<16 | src  (needs N < 65536).
// ---------------------------------------------------------------------------
__global__ void binprep_kernel(const int* __restrict__ dst,
                               const int* __restrict__ src, int E, int cap,
                               const float* __restrict__ x, int M,
                               int* __restrict__ ccur,
                               unsigned* __restrict__ packed,
                               unsigned short* __restrict__ tm,
                               int binBlocks) {
    if ((int)blockIdx.x < binBlocks) {
        __shared__ int lc[256];
        __shared__ int lbase[256];
        int tid = threadIdx.x;
        lc[tid] = 0;
        __syncthreads();
        int e0 = blockIdx.x * 4096;
        int bb[16], rr[16];
        unsigned pk[16];
        #pragma unroll
        for (int i = 0; i < 16; ++i) {
            int e = e0 + i * 256 + tid;
            bb[i] = 0; rr[i] = 0; pk[i] = 0;
            if (e < E) {
                int d = dst[e];
                bb[i] = d >> 8;
                pk[i] = ((unsigned)(d & 255) << 16) | (unsigned)src[e];
                rr[i] = atomicAdd(&lc[bb[i]], 1);
            }
        }
        __syncthreads();
        int c = lc[tid];
        if (c) lbase[tid] = tid * cap + atomicAdd(&ccur[tid], c);
        __syncthreads();
        #pragma unroll
        for (int i = 0; i < 16; ++i) {
            int e = e0 + i * 256 + tid;
            if (e < E) packed[lbase[bb[i]] + rr[i]] = pk[i];
        }
    } else {
        int blk = blockIdx.x - binBlocks;
        int tid = threadIdx.x;
        const unsigned short sent = __half_as_ushort(__float2half_rn(-32.f));
        #pragma unroll
        for (int p = 0; p < 4; ++p) {
            int i = blk * 4096 + p * 1024 + tid * 4;
            if (i < M) {
                float4 v = *(const float4*)&x[i];
                ushort4 o;
                o.x = __half_as_ushort(__float2half_rn(fmaxf(v.x, 0.f) + EPS));
                o.y = __half_as_ushort(__float2half_rn(fmaxf(v.y, 0.f) + EPS));
                o.z = __half_as_ushort(__float2half_rn(fmaxf(v.z, 0.f) + EPS));
                o.w = __half_as_ushort(__float2half_rn(fmaxf(v.w, 0.f) + EPS));
                *(ushort4*)&tm[i] = o;
            } else if (i < M + 64) {
                ushort4 o; o.x = o.y = o.z = o.w = sent;
                *(ushort4*)&tm[i] = o;
            }
        }
    }
}

// ---------------------------------------------------------------------------
// Phase 2: one block per bucket. Stage packed window in LDS; in-LDS hist of
// dst-low-byte -> scan -> per-node (start,end) as int2 + LDS fine scatter,
// then fully-coalesced u32-pair write of the u16 sorted_src window.
// ---------------------------------------------------------------------------
__global__ void fine_kernel(const unsigned* __restrict__ packed,
                            const int* __restrict__ ccur, int cap,
                            int2* __restrict__ nse,
                            unsigned short* __restrict__ sorted_src, int N) {
    __shared__ int lc[256];
    __shared__ int lcur[256];
    __shared__ int wsum[4];
    __shared__ unsigned stage_pk[6656];
    __shared__ unsigned short stage16[6656];
    int tid = threadIdx.x, b = blockIdx.x;
    int rs = b * cap;
    int len = ccur[b];
    lc[tid] = 0;
    __syncthreads();
    for (int i = tid; i < len; i += 256) {
        unsigned u = packed[rs + i];
        stage_pk[i] = u;
        atomicAdd(&lc[u >> 16], 1);
    }
    __syncthreads();
    // 256-wide exclusive scan of lc
    int lane = tid & 63, wid = tid >> 6;
    int v = lc[tid];
    int incl = v;
    #pragma unroll
    for (int d = 1; d < 64; d <<= 1) {
        int t = __shfl_up(incl, d, 64);
        if (lane >= d) incl += t;
    }
    if (lane == 63) wsum[wid] = incl;
    __syncthreads();
    int base = 0;
    for (int w = 0; w < wid; ++w) base += wsum[w];
    int excl = base + incl - v;
    lcur[tid] = excl;
    int node = b * 256 + tid;
    if (node < N) nse[node] = make_int2(rs + excl, rs + excl + v);
    __syncthreads();
    for (int i = tid; i < len; i += 256) {
        unsigned u = stage_pk[i];
        int pos = atomicAdd(&lcur[u >> 16], 1);
        stage16[pos] = (unsigned short)(u & 0xffffu);
    }
    __syncthreads();
    // coalesced copy out (rs is 256-aligned -> u32 writes aligned)
    unsigned* dst32 = (unsigned*)&sorted_src[rs];
    int len2 = (len + 1) >> 1;
    for (int i = tid; i < len2; i += 256) {
        unsigned lo = stage16[2 * i];
        unsigned hi = (2 * i + 1 < len) ? (unsigned)stage16[2 * i + 1] : 0u;
        dst32[i] = lo | (hi << 16);
    }
}

// ---------------------------------------------------------------------------
// Per-node fused softmax-aggregate + linear. Quarter-wave gather: lane owns
// channels 4*(lane&15)..+3 via one dwordx2 (fp16 m values); 4 edges in
// flight (quarter = lane>>4). exp(beta*m) computed in-register (quarter-rate
// v_exp, ~2.6us device-wide total). shfl_xor(16,32) combines quarters.
// Epilogue: agg @ W^T from LDS (stride 65 -> free 2-way bank aliasing).
// ---------------------------------------------------------------------------
__device__ __forceinline__ void acc2(unsigned w, float bt,
                                     float& s1a, float& s2a,
                                     float& s1b, float& s2b) {
    float m0 = __half2float(__ushort_as_half((unsigned short)(w & 0xffffu)));
    float m1 = __half2float(__ushort_as_half((unsigned short)(w >> 16)));
    float e0 = __expf(bt * m0);
    float e1 = __expf(bt * m1);
    s1a += e0; s2a = fmaf(m0, e0, s2a);
    s1b += e1; s2b = fmaf(m1, e1, s2b);
}

__launch_bounds__(256)
__global__ void node_kernel(const unsigned short* __restrict__ tm,
                            const int2* __restrict__ nse,
                            const unsigned short* __restrict__ sorted_src,
                            const float* __restrict__ W,
                            const float* __restrict__ b,
                            const float* __restrict__ beta,
                            float* __restrict__ out, int N) {
    __shared__ float WtS[64 * 65];
    __shared__ float aggS[256];

    int tid = threadIdx.x;
    for (int idx = tid * 4; idx < 64 * 64; idx += 256 * 4) {
        float4 w4 = *(const float4*)&W[idx];
        int j = idx >> 6, c = idx & 63;
        WtS[(c + 0) * 65 + j] = w4.x;
        WtS[(c + 1) * 65 + j] = w4.y;
        WtS[(c + 2) * 65 + j] = w4.z;
        WtS[(c + 3) * 65 + j] = w4.w;
    }
    __syncthreads();

    const float bt = beta[0];
    const int wave = tid >> 6;
    const int lane = tid & 63;
    const int quarter = lane >> 4;
    const int chb = (lane & 15) << 3;      // byte offset of channel quad
    const float bias = b[lane];
    const int stride = gridDim.x * 4;
    const int sent_row = N << 7;           // byte offset of sentinel row
    const unsigned char* tmb = (const unsigned char*)tm;
    float* as = &aggS[wave * 64];          // wave-private

    for (int node = blockIdx.x * 4 + wave; node < N; node += stride) {
        int2 se = nse[node];
        int start = se.x, end = se.y;
        float s1c0 = 0.f, s1c1 = 0.f, s1c2 = 0.f, s1c3 = 0.f;
        float s2c0 = 0.f, s2c1 = 0.f, s2c2 = 0.f, s2c3 = 0.f;
        for (int bse = start; bse < end; bse += 64) {
            int cnt = end - bse;
            if (cnt > 64) cnt = 64;
            // lane L holds edge bse+L's row byte-offset; pad -> sentinel row
            int row = (lane < cnt) ? ((int)sorted_src[bse + lane] << 7)
                                   : sent_row;
            for (int k = 0; k < cnt; k += 8) {
                int r0 = __shfl(row, k + quarter, 64);
                int r1 = __shfl(row, k + 4 + quarter, 64);
                uint2 u0 = *(const uint2*)(tmb + (r0 + chb));
                uint2 u1 = *(const uint2*)(tmb + (r1 + chb));
                acc2(u0.x, bt, s1c0, s2c0, s1c1, s2c1);
                acc2(u0.y, bt, s1c2, s2c2, s1c3, s2c3);
                acc2(u1.x, bt, s1c0, s2c0, s1c1, s2c1);
                acc2(u1.y, bt, s1c2, s2c2, s1c3, s2c3);
            }
        }
        // combine the 4 quarters
        #define RED(s) s += __shfl_xor(s, 16, 64); s += __shfl_xor(s, 32, 64)
        RED(s1c0); RED(s1c1); RED(s1c2); RED(s1c3);
        RED(s2c0); RED(s2c1); RED(s2c2); RED(s2c3);
        #undef RED
        float4 g;
        g.x = s2c0 / (s1c0 + 1e-16f);
        g.y = s2c1 / (s1c1 + 1e-16f);
        g.z = s2c2 / (s1c2 + 1e-16f);
        g.w = s2c3 / (s1c3 + 1e-16f);
        if (lane < 16) *(float4*)&as[(lane & 15) << 2] = g;
        float acc = bias;
        #pragma unroll
        for (int c = 0; c < 64; c += 4) {
            float4 a4 = *(const float4*)&as[c];  // uniform addr -> broadcast
            acc = fmaf(a4.x, WtS[(c + 0) * 65 + lane], acc);
            acc = fmaf(a4.y, WtS[(c + 1) * 65 + lane], acc);
            acc = fmaf(a4.z, WtS[(c + 2) * 65 + lane], acc);
            acc = fmaf(a4.w, WtS[(c + 3) * 65 + lane], acc);
        }
        out[(size_t)node * 64 + lane] = acc;
    }
}

// ---------------------------------------------------------------------------
// launch
// ---------------------------------------------------------------------------
extern "C" void kernel_launch(void* const* d_in, const int* in_sizes, int n_in,
                              void* d_out, int out_size, void* d_ws, size_t ws_size,
                              hipStream_t stream) {
    const float* x    = (const float*)d_in[0];
    const int*   ei   = (const int*)d_in[1];    // [2, E]: row0 = dst, row1 = src
    const float* W    = (const float*)d_in[2];
    const float* b    = (const float*)d_in[3];
    const float* beta = (const float*)d_in[4];
    float* out = (float*)d_out;

    const int N = in_sizes[0] / 64;
    const int E = in_sizes[1] / 2;
    const int* dst = ei;
    const int* src = ei + E;
    const int NB = (N + 255) >> 8;              // 196 coarse buckets
    const int M = N * 64;

    // fixed per-bucket capacity: mean + 50% + 256, rounded up to 256 (<=6656)
    int cap = (E + NB - 1) / NB;
    cap = ((cap + cap / 2 + 256) + 255) & ~255;
    if (cap > 6656) cap = 6656;

    auto align = [](size_t v) { return (v + 255) & ~(size_t)255; };
    size_t off = 0;
    char* ws = (char*)d_ws;
    int2* nse   = (int2*)(ws + off);      off += align((size_t)N * 8);
    int* ccur   = (int*)(ws + off);       off += align((size_t)NB * 4);
    unsigned* packed = (unsigned*)(ws + off);
    off += align((size_t)NB * cap * 4);
    unsigned short* sorted_src = (unsigned short*)(ws + off);
    off += align((size_t)NB * cap * 2);
    unsigned short* tm = (unsigned short*)(ws + off);  // (N+1)*64 fp16

    const int binBlocks  = (E + 4095) / 4096;          // 196
    const int prepBlocks = (M + 64 + 4095) / 4096;     // 782
    hipMemsetAsync(ccur, 0, (size_t)NB * 4, stream);
    binprep_kernel<<<binBlocks + prepBlocks, 256, 0, stream>>>(
        dst, src, E, cap, x, M, ccur, packed, tm, binBlocks);
    fine_kernel<<<NB, 256, 0, stream>>>(packed, ccur, cap, nse, sorted_src, N);

    int node_blocks = (N + 3) / 4;
    if (node_blocks > 2048) node_blocks = 2048;  // 8 blocks/CU (LDS-limited)
    node_kernel<<<node_blocks, 256, 0, stream>>>(tm, nse, sorted_src,
                                                 W, b, beta, out, N);
}